// Round 2
// baseline (156.001 us; speedup 1.0000x reference)
//
#include <hip/hip_runtime.h>

// BoxFilter: separable clamped box-SUM, radius 4, on (32,8,512,512) fp32.
// Wave-per-strip design: each 64-lane wave owns a full 512-wide row strip
// (8 columns/lane in two float4 accumulators). Vertical running-window sum
// in registers; horizontal 9-tap via 8 lane-shuffles. No LDS, no barriers.

constexpr int H      = 512;
constexpr int W      = 512;
constexpr int RAD    = 4;        // fixed by setup_inputs (r = 4)
constexpr int TH     = 16;       // output rows per wave
constexpr int NSTRIP = H / TH;   // 32 strips per image
constexpr int WPB    = 4;        // waves per block
constexpr int NT     = WPB * 64; // 256 threads
constexpr int W4     = W / 4;    // 128 float4 per row

__device__ __forceinline__ void add4(float4& d, const float4 a) {
    d.x += a.x; d.y += a.y; d.z += a.z; d.w += a.w;
}
__device__ __forceinline__ void sub4(float4& d, const float4 a) {
    d.x -= a.x; d.y -= a.y; d.z -= a.z; d.w -= a.w;
}

template<bool TOP, bool BOT>
__device__ __forceinline__ void do_strip(const float4* __restrict__ x4,
                                         float4* __restrict__ o4,
                                         const int R0, const int lane) {
    const int cb = lane * 2;   // this lane's float4 column base (cols 8*lane..)

    // ---- vertical prologue: sum rows max(0,R0-4) .. R0+4 ----
    float4 s0 = {0.f, 0.f, 0.f, 0.f}, s1 = {0.f, 0.f, 0.f, 0.f};
    {
        const int k0 = TOP ? 0 : (R0 - RAD);
        for (int k = k0; k <= R0 + RAD; ++k) {
            add4(s0, x4[k * W4 + cb]);
            add4(s1, x4[k * W4 + cb + 1]);
        }
    }

    #pragma unroll 2
    for (int ii = 0; ii < TH; ++ii) {
        const int i = R0 + ii;
        if (ii > 0) {
            if (!BOT || (i + RAD < H)) {          // compile-time true for interior
                add4(s0, x4[(i + RAD) * W4 + cb]);
                add4(s1, x4[(i + RAD) * W4 + cb + 1]);
            }
            if (!TOP || (i - RAD - 1 >= 0)) {     // compile-time true for interior
                sub4(s0, x4[(i - RAD - 1) * W4 + cb]);
                sub4(s1, x4[(i - RAD - 1) * W4 + cb + 1]);
            }
        }

        // ---- horizontal 9-tap: neighbors via shuffle, clamped edges -> 0 ----
        // L = lane-1's s1 (cols 8t-4..8t-1), R = lane+1's s0 (cols 8t+8..8t+11)
        float4 L, R;
        L.x = __shfl_up(s1.x, 1); L.y = __shfl_up(s1.y, 1);
        L.z = __shfl_up(s1.z, 1); L.w = __shfl_up(s1.w, 1);
        R.x = __shfl_down(s0.x, 1); R.y = __shfl_down(s0.y, 1);
        R.z = __shfl_down(s0.z, 1); R.w = __shfl_down(s0.w, 1);
        if (lane == 0)  { L.x = L.y = L.z = L.w = 0.f; }
        if (lane == 63) { R.x = R.y = R.z = R.w = 0.f; }

        const float o0 = ((L.x + L.y) + (L.z + L.w))
                       + ((s0.x + s0.y) + (s0.z + s0.w)) + s1.x;
        const float o1 = o0 - L.x + s1.y;
        const float o2 = o1 - L.y + s1.z;
        const float o3 = o2 - L.z + s1.w;
        const float o4v = o3 - L.w + R.x;
        const float o5 = o4v - s0.x + R.y;
        const float o6 = o5 - s0.y + R.z;
        const float o7 = o6 - s0.z + R.w;

        o4[(size_t)i * W4 + cb]     = make_float4(o0, o1, o2, o3);
        o4[(size_t)i * W4 + cb + 1] = make_float4(o4v, o5, o6, o7);
    }
}

__global__ __launch_bounds__(NT, 8)
void BoxFilter_90331752169653_kernel(const float* __restrict__ x,
                                     float* __restrict__ out) {
    const int img  = blockIdx.y;
    const int wid  = threadIdx.x >> 6;
    const int lane = threadIdx.x & 63;
    const int strip = blockIdx.x * WPB + wid;

    const float4* __restrict__ x4 = (const float4*)(x + (size_t)img * H * W);
    float4* __restrict__ o4       = (float4*)(out + (size_t)img * H * W);

    if (strip == 0)                 do_strip<true,  false>(x4, o4, 0,       lane);
    else if (strip == NSTRIP - 1)   do_strip<false, true >(x4, o4, H - TH,  lane);
    else                            do_strip<false, false>(x4, o4, strip * TH, lane);
}

extern "C" void kernel_launch(void* const* d_in, const int* in_sizes, int n_in,
                              void* d_out, int out_size, void* d_ws, size_t ws_size,
                              hipStream_t stream) {
    const float* x = (const float*)d_in[0];
    float* out    = (float*)d_out;
    const int n_img = in_sizes[0] / (H * W); // 32*8 = 256 images
    dim3 grid(NSTRIP / WPB, n_img);
    BoxFilter_90331752169653_kernel<<<grid, NT, 0, stream>>>(x, out);
}

// Round 3
// 112.075 us; speedup vs baseline: 1.3919x; 1.3919x over previous
//
#include <hip/hip_runtime.h>

// BoxFilter: separable clamped box-SUM, radius 4, on (32,8,512,512) fp32.
// Block = 128 threads (2 waves) owns a 64-row x 512-col strip.
// Vertical pass: 9-row register ring buffer -> each input row loaded EXACTLY
// once (no L2-dependent re-reads). Horizontal pass: padded LDS row chunk,
// 8 rows per barrier pair. Fully coalesced float4 loads/stores.

constexpr int H    = 512;
constexpr int W    = 512;
constexpr int RAD  = 4;          // fixed by setup_inputs (r = 4)
constexpr int TH   = 64;         // rows per block
constexpr int CH   = 8;          // rows per chunk (per barrier pair)
constexpr int NCH  = TH / CH;    // 8 chunks
constexpr int NT   = 128;        // threads (thread t <-> float4 column t)
constexpr int W4   = W / 4;      // 128 float4 per row
constexpr int PADW = W + 2 * RAD; // 520 floats per padded LDS row

__device__ __forceinline__ void add4(float4& d, const float4 a) {
    d.x += a.x; d.y += a.y; d.z += a.z; d.w += a.w;
}

template<bool TOP, bool BOT>
__device__ __forceinline__ void do_strip(const float4* __restrict__ x4,
                                         float4* __restrict__ o4,
                                         const int R0, const int t,
                                         float* __restrict__ lds) {
    // zero the RAD-wide pads of all CH LDS rows (written once, never touched again)
    if (t < CH * 8) {
        const int r = t >> 3, c = t & 7;
        lds[r * PADW + (c < RAD ? c : W + c)] = 0.f;   // c in 4..7 -> 516..519
    }

    // ---- init: ring = x[R0-5 .. R0+3] (zeros out-of-range), s = sum(ring) ----
    float4 ring[2 * RAD + 1];                          // 9 rows
    float4 s = {0.f, 0.f, 0.f, 0.f};
    #pragma unroll
    for (int k = 0; k < 2 * RAD + 1; ++k) {
        if (TOP && k < RAD + 1) {                      // rows -5..-1 (R0 == 0)
            ring[k] = make_float4(0.f, 0.f, 0.f, 0.f);
        } else {
            ring[k] = x4[(R0 - RAD - 1 + k) * W4 + t];
            add4(s, ring[k]);
        }
    }
    // invariant entering row i: ring = x[i-5..i+3], s = s(i-1) (window at i-1)

    for (int c = 0; c < NCH; ++c) {
        const int base = R0 + c * CH;

        // ---- phase 1: vertical running sums for CH rows -> LDS ----
        #pragma unroll
        for (int ii = 0; ii < CH; ++ii) {
            const int i = base + ii;
            float4 n;
            if (!BOT || (c * CH + ii < TH - RAD)) {    // compile-time per slot
                n = x4[(i + RAD) * W4 + t];
            } else {
                n = make_float4(0.f, 0.f, 0.f, 0.f);   // clamped bottom rows
            }
            s.x += n.x - ring[0].x; s.y += n.y - ring[0].y;
            s.z += n.z - ring[0].z; s.w += n.w - ring[0].w;
            #pragma unroll
            for (int k = 0; k < 2 * RAD; ++k) ring[k] = ring[k + 1];  // SSA renames
            ring[2 * RAD] = n;
            *(float4*)&lds[ii * PADW + RAD + 4 * t] = s;
        }
        __syncthreads();

        // ---- phase 2: horizontal 9-tap from LDS, coalesced stores ----
        #pragma unroll
        for (int ii = 0; ii < CH; ++ii) {
            const int i = base + ii;
            const float* rr = &lds[ii * PADW];
            const float4 A = *(const float4*)&rr[4 * t];          // cols 4t-4..4t-1
            const float4 M = *(const float4*)&rr[4 * t + 4];      // cols 4t  ..4t+3
            const float4 C = *(const float4*)&rr[4 * t + 8];      // cols 4t+4..4t+7
            const float o0 = ((A.x + A.y) + (A.z + A.w))
                           + ((M.x + M.y) + (M.z + M.w)) + C.x;
            const float o1 = o0 - A.x + C.y;
            const float o2 = o1 - A.y + C.z;
            const float o3 = o2 - A.z + C.w;
            o4[(size_t)i * W4 + t] = make_float4(o0, o1, o2, o3);
        }
        __syncthreads();   // protect LDS before next chunk's phase-1 writes
    }
}

__global__ __launch_bounds__(NT, 4)
void BoxFilter_90331752169653_kernel(const float* __restrict__ x,
                                     float* __restrict__ out) {
    __shared__ __align__(16) float lds[CH * PADW];

    const int img   = blockIdx.y;
    const int strip = blockIdx.x;
    const int t     = threadIdx.x;

    const float4* __restrict__ x4 = (const float4*)(x + (size_t)img * H * W);
    float4* __restrict__ o4       = (float4*)(out + (size_t)img * H * W);

    if (strip == 0)                   do_strip<true,  false>(x4, o4, 0,          t, lds);
    else if (strip == (H / TH) - 1)   do_strip<false, true >(x4, o4, H - TH,     t, lds);
    else                              do_strip<false, false>(x4, o4, strip * TH, t, lds);
}

extern "C" void kernel_launch(void* const* d_in, const int* in_sizes, int n_in,
                              void* d_out, int out_size, void* d_ws, size_t ws_size,
                              hipStream_t stream) {
    const float* x = (const float*)d_in[0];
    float* out    = (float*)d_out;
    const int n_img = in_sizes[0] / (H * W);   // 32*8 = 256 images
    dim3 grid(H / TH, n_img);                  // 8 x 256 = 2048 blocks
    BoxFilter_90331752169653_kernel<<<grid, NT, 0, stream>>>(x, out);
}

// Round 5
// 87.968 us; speedup vs baseline: 1.7734x; 1.2741x over previous
//
#include <hip/hip_runtime.h>

// BoxFilter: separable clamped box-SUM, radius 4, on (32,8,512,512) fp32.
// Wave-per-strip, ZERO block barriers: each 64-lane wave owns a 64-row x
// 512-col strip (lane i <-> float4 cols i and 64+i, globally contiguous).
// Vertical: 9-row register ring (each input row loaded exactly once).
// Horizontal: wave-PRIVATE padded LDS row. Cross-lane LDS sharing within a
// wave is ordered by an explicit lgkmcnt(0)+memory fence (R3 bug: without
// it the compiler hoists the neighbor ds_reads above the ds_writes — the
// accesses don't alias in per-thread semantics). vmcnt never drains;
// chunked double-buffered prefetch keeps global loads in flight.

typedef float fvec4 __attribute__((ext_vector_type(4)));

constexpr int H    = 512;
constexpr int W    = 512;
constexpr int RAD  = 4;          // fixed by setup_inputs (r = 4)
constexpr int TH   = 64;         // rows per wave (strip)
constexpr int CH   = 4;          // rows per prefetch chunk
constexpr int NCH  = TH / CH;    // 16 chunks
constexpr int WPB  = 4;          // waves (strips) per block
constexpr int NT   = WPB * 64;   // 256 threads
constexpr int W4   = W / 4;      // 128 float4 per row
constexpr int PADW = 528;        // padded LDS row (floats); 520 used

// Order ds_write -> cross-lane ds_read within one wave:
//  - "memory" clobber: IR-level fence, compiler cannot hoist reads above
//  - s_waitcnt lgkmcnt(0): HW-level write-retire before the reads issue
__device__ __forceinline__ void wave_lds_fence() {
    asm volatile("s_waitcnt lgkmcnt(0)" ::: "memory");
}

template<bool TOP, bool BOT>
__device__ __forceinline__ void do_strip(const fvec4* __restrict__ x4,
                                         fvec4* __restrict__ o4,
                                         const int R0, const int lane,
                                         float* __restrict__ lds) {
    // zero the 4-float pads at both ends of this wave's LDS row (once)
    if (lane < 8) lds[lane < 4 ? lane : 512 + lane] = 0.f;  // 0..3, 516..519

    // ---- ring = x[R0-5 .. R0+3] (zeros out-of-range); s = sum(ring) ----
    fvec4 r0[9], r1[9];
    fvec4 s0 = {0.f, 0.f, 0.f, 0.f}, s1 = {0.f, 0.f, 0.f, 0.f};
    #pragma unroll
    for (int k = 0; k < 9; ++k) {
        const int row = R0 - 5 + k;
        if (TOP && k < 5) {
            r0[k] = s0 - s0; r1[k] = s0 - s0;      // zeros
        } else {
            r0[k] = x4[row * W4 + lane];
            r1[k] = x4[row * W4 + 64 + lane];
            s0 += r0[k]; s1 += r1[k];
        }
    }
    // invariant entering row i: ring = x[i-5..i+3], s = window(i-1)

    // ---- chunk-0 lookahead: rows R0+4 .. R0+4+CH-1 (always in-image) ----
    fvec4 A0[CH], A1[CH], B0[CH], B1[CH];
    #pragma unroll
    for (int ii = 0; ii < CH; ++ii) {
        A0[ii] = x4[(R0 + RAD + ii) * W4 + lane];
        A1[ii] = x4[(R0 + RAD + ii) * W4 + 64 + lane];
    }

    #pragma unroll
    for (int c = 0; c < NCH; ++c) {
        // issue next chunk's loads (stay in flight through this chunk's work)
        if (c + 1 < NCH) {
            #pragma unroll
            for (int ii = 0; ii < CH; ++ii) {
                const int row = R0 + (c + 1) * CH + RAD + ii;
                fvec4 n0, n1;
                if (BOT && row >= H) {               // compile-time per slot
                    n0 = s0 - s0; n1 = n0;
                } else {
                    n0 = x4[row * W4 + lane];
                    n1 = x4[row * W4 + 64 + lane];
                }
                if (c & 1) { A0[ii] = n0; A1[ii] = n1; }
                else       { B0[ii] = n0; B1[ii] = n1; }
            }
        }

        #pragma unroll
        for (int ii = 0; ii < CH; ++ii) {
            const int i = R0 + c * CH + ii;
            const fvec4 n0 = (c & 1) ? B0[ii] : A0[ii];
            const fvec4 n1 = (c & 1) ? B1[ii] : A1[ii];

            // vertical running-window update (x[i+4] - x[i-5])
            s0 += n0 - r0[0];
            s1 += n1 - r1[0];
            #pragma unroll
            for (int k = 0; k < 8; ++k) { r0[k] = r0[k + 1]; r1[k] = r1[k + 1]; }
            r0[8] = n0; r1[8] = n1;

            // stage vertical sums in this wave's private padded LDS row
            *(fvec4*)&lds[RAD + 4 * lane]       = s0;   // cols 4i   .. 4i+3
            *(fvec4*)&lds[RAD + 256 + 4 * lane] = s1;   // cols 256+4i ..

            wave_lds_fence();   // ds_writes retired; reads may not hoist

            const fvec4 La = *(const fvec4*)&lds[4 * lane];             // 4i-4..
            const fvec4 Ca = *(const fvec4*)&lds[RAD + 4 * lane + 4];   // 4i+4..
            const fvec4 Lb = *(const fvec4*)&lds[256 + 4 * lane];
            const fvec4 Cb = *(const fvec4*)&lds[RAD + 256 + 4 * lane + 4];

            // horizontal 9-tap (pads are zeros -> clamped edges correct)
            const float o0 = ((La.x + La.y) + (La.z + La.w))
                           + ((s0.x + s0.y) + (s0.z + s0.w)) + Ca.x;
            const float o1 = o0 - La.x + Ca.y;
            const float o2 = o1 - La.y + Ca.z;
            const float o3 = o2 - La.z + Ca.w;
            const float p0 = ((Lb.x + Lb.y) + (Lb.z + Lb.w))
                           + ((s1.x + s1.y) + (s1.z + s1.w)) + Cb.x;
            const float p1 = p0 - Lb.x + Cb.y;
            const float p2 = p1 - Lb.y + Cb.z;
            const float p3 = p2 - Lb.z + Cb.w;

            fvec4 out0 = {o0, o1, o2, o3};
            fvec4 out1 = {p0, p1, p2, p3};
            __builtin_nontemporal_store(out0, &o4[(size_t)i * W4 + lane]);
            __builtin_nontemporal_store(out1, &o4[(size_t)i * W4 + 64 + lane]);
        }
    }
}

__global__ __launch_bounds__(NT, 2)
void BoxFilter_90331752169653_kernel(const float* __restrict__ x,
                                     float* __restrict__ out) {
    __shared__ __align__(16) float lds[WPB * PADW];

    const int img  = blockIdx.y;
    const int wid  = threadIdx.x >> 6;
    const int lane = threadIdx.x & 63;
    const int strip = blockIdx.x * WPB + wid;          // 0..7

    const fvec4* __restrict__ x4 = (const fvec4*)(x + (size_t)img * H * W);
    fvec4* __restrict__ o4       = (fvec4*)(out + (size_t)img * H * W);
    float* myLds = &lds[wid * PADW];

    if (strip == 0)                   do_strip<true,  false>(x4, o4, 0,          lane, myLds);
    else if (strip == (H / TH) - 1)   do_strip<false, true >(x4, o4, H - TH,     lane, myLds);
    else                              do_strip<false, false>(x4, o4, strip * TH, lane, myLds);
}

extern "C" void kernel_launch(void* const* d_in, const int* in_sizes, int n_in,
                              void* d_out, int out_size, void* d_ws, size_t ws_size,
                              hipStream_t stream) {
    const float* x = (const float*)d_in[0];
    float* out    = (float*)d_out;
    const int n_img = in_sizes[0] / (H * W);   // 32*8 = 256 images
    dim3 grid((H / TH) / WPB, n_img);          // 2 x 256 = 512 blocks
    BoxFilter_90331752169653_kernel<<<grid, NT, 0, stream>>>(x, out);
}